// Round 10
// baseline (655.671 us; speedup 1.0000x reference)
//
#include <hip/hip_runtime.h>
#include <hip/hip_bf16.h>
#include <stdint.h>

typedef __hip_bfloat16 bf16;
typedef __attribute__((ext_vector_type(8))) short short8;   // 8 bf16 = 4 VGPRs
typedef __attribute__((ext_vector_type(4))) float float4v;  // MFMA C/D
typedef __attribute__((ext_vector_type(4))) short short4v;

__device__ __forceinline__ short f2bs(float x) {
    bf16 b = __float2bfloat16(x);
    return *reinterpret_cast<short*>(&b);
}
__device__ __forceinline__ float bs2f(short s) {
    bf16 b = *reinterpret_cast<bf16*>(&s);
    return __bfloat162float(b);
}

#define GLL16(g, l) __builtin_amdgcn_global_load_lds(                      \
    (const __attribute__((address_space(1))) void*)(g),                    \
    (__attribute__((address_space(3))) void*)(l), 16, 0, 0)

// ---------------- preprocessing: f32 -> padded bf16 layouts ----------------

__global__ __launch_bounds__(256) void conv_emb(
    const float* __restrict__ src, short* __restrict__ dst)
{
    const int idx = blockIdx.x * 256 + threadIdx.x;      // 50000*80
    if (idx >= 50000 * 80) return;
    const int row = idx / 80;
    const int k4  = (idx - row * 80) * 4;
    short4v v;
#pragma unroll
    for (int j = 0; j < 4; ++j)
        v[j] = (k4 + j < 300) ? f2bs(src[(long)row * 300 + k4 + j]) : (short)0;
    *(short4v*)&dst[(long)row * 320 + k4] = v;
}

__global__ __launch_bounds__(256) void conv_wleaf(
    const float* __restrict__ src, short* __restrict__ dst)
{
    const int idx = blockIdx.x * 256 + threadIdx.x;      // 320*320
    if (idx >= 320 * 320) return;
    const int row = idx / 320, k = idx - row * 320;
    dst[idx] = (row < 300 && k < 300) ? f2bs(src[row * 300 + k]) : (short)0;
}

__global__ __launch_bounds__(256) void conv_wh(
    const float* __restrict__ src, short* __restrict__ dst)
{
    const int idx = blockIdx.x * 256 + threadIdx.x;      // 320*640
    if (idx >= 320 * 640) return;
    const int row = idx / 640, k = idx - row * 640;
    float v = 0.f;
    if (row < 300) {
        if (k < 300)                  v = src[row * 600 + k];
        else if (k >= 320 && k < 620) v = src[row * 600 + k - 20];
    }
    dst[idx] = f2bs(v);
}

__global__ __launch_bounds__(320) void conv_bias(
    const float* __restrict__ src, float* __restrict__ dst)
{
    const int i = threadIdx.x;
    if (i < 320) dst[i] = (i < 300) ? src[i] : 0.f;
}

// ---------------- MFMA GEMM (R9 + BK=64: half the barrier drains) ----------
// out(M,320 bf16) = X(M,KE bf16) @ Wp(320,KE bf16)^T (+ biasp), KE in {320,640}.
// Block: 256 thr = 4 waves 2x2; tile M=128 x N=320 (full N -> ideal writes).
// Wave: 64x160 = 4 M-tiles x 10 N-tiles of v_mfma_f32_16x16x32_bf16.
// K-chunk = 64 (2 MFMA k-steps per barrier): leaf 5 chunks, tree 10 chunks.
// LDS rows of 128 B, 8 slots of 16 B; stored slot s holds global k-slot
// q = s ^ (row&7)  -> GLL16 dst stays linear (wave-uniform base + lane*16),
// ds_read_b128 is bank-BW-bound (no extra conflict). h-th k-half of a row:
// logical slot q = h*4+kq -> stored s = q^(row&7); h toggles addr bit 6.
// MFMA operands swapped (b,a) [R6-verified]: acc[t][u] reg r4 =
//   C[row = t-tile + (lane&15)][col = u-tile + (lane>>4)*4 + r4].
template <int KE, bool GATHER, bool BIAS>
__global__ __launch_bounds__(256, 2) void mfma_gemm(
    const short* __restrict__ Xsrc, const int* __restrict__ wid,
    const short* __restrict__ emb, const short* __restrict__ Wp,
    const float* __restrict__ biasp, short* __restrict__ out)
{
    __shared__ __align__(16) short As[128 * 64];   // 16 KB
    __shared__ __align__(16) short Bs[320 * 64];   // 40 KB

    const int tid  = threadIdx.x;
    const int lane = tid & 63;
    const int w    = tid >> 6;
    const int wm   = w >> 1, wn = w & 1;
    const long m0  = (long)blockIdx.x * 128;

    const int s_q   = lane & 7;     // lane's stored 16-B slot within 128-B row
    const int r_off = lane >> 3;    // row within 8-row staging group
    const int q_g   = s_q ^ r_off;  // global k-slot this lane fetches

    // A: 16 groups of 8 rows; wave w handles groups w+4j, j=0..3
    const char* gA[4];
    char*       lA[4];
#pragma unroll
    for (int j = 0; j < 4; ++j) {
        const int g = w + 4 * j;
        const int r = g * 8 + r_off;                       // A row 0..127
        long base;
        if (GATHER) base = (long)wid[m0 + r] * 640;
        else        base = (m0 + r) * (long)(KE * 2);
        gA[j] = (const char*)(GATHER ? emb : Xsrc) + base + q_g * 16;
        lA[j] = (char*)As + g * 1024;
    }
    // B: 40 groups of 8 rows; wave w handles groups w+4j, j=0..9
    const char* gB[10];
    char*       lB[10];
#pragma unroll
    for (int j = 0; j < 10; ++j) {
        const int g = w + 4 * j;
        const int r = g * 8 + r_off;                       // B row 0..319
        gB[j] = (const char*)Wp + (long)r * (KE * 2) + q_g * 16;
        lB[j] = (char*)Bs + g * 1024;
    }

    // fragment LDS addresses for k-half h=0 (h=1: XOR byte addr with 64)
    const int mq = lane & 15, kq = lane >> 4;
    const short* fA[4];
#pragma unroll
    for (int t = 0; t < 4; ++t) {
        const int row = wm * 64 + t * 16 + mq;
        const int s0  = kq ^ (row & 7);
        fA[t] = &As[row * 64 + s0 * 8];
    }
    const short* fB[10];
#pragma unroll
    for (int u = 0; u < 10; ++u) {
        const int n  = wn * 160 + u * 16 + mq;
        const int s0 = kq ^ (n & 7);
        fB[u] = &Bs[n * 64 + s0 * 8];
    }

    float4v acc[4][10];
#pragma unroll
    for (int t = 0; t < 4; ++t)
#pragma unroll
        for (int u = 0; u < 10; ++u) acc[t][u] = (float4v)0.f;

    for (int kc = 0; kc < KE / 64; ++kc) {
        if (kc) __syncthreads();           // all waves done reading prev chunk
        const int off = kc * 128;
#pragma unroll
        for (int j = 0; j < 4; ++j)  GLL16(gA[j] + off, lA[j]);
#pragma unroll
        for (int j = 0; j < 10; ++j) GLL16(gB[j] + off, lB[j]);
        __syncthreads();                   // drains vmcnt -> LDS visible

#pragma unroll
        for (int h = 0; h < 2; ++h) {
            const uintptr_t hx = h * 64;   // toggles stored-slot bit 2
            short8 a[4], b[10];
#pragma unroll
            for (int t = 0; t < 4; ++t)
                a[t] = *(const short8*)((uintptr_t)fA[t] ^ hx);
#pragma unroll
            for (int u = 0; u < 10; ++u)
                b[u] = *(const short8*)((uintptr_t)fB[u] ^ hx);
#pragma unroll
            for (int u = 0; u < 10; ++u)
#pragma unroll
                for (int t = 0; t < 4; ++t)
                    acc[t][u] = __builtin_amdgcn_mfma_f32_16x16x32_bf16(
                        b[u], a[t], acc[t][u], 0, 0, 0);   // swapped operands
        }
    }

    // epilogue: row = X row (lane&15); 4 consecutive cols at (lane>>4)*4
#pragma unroll
    for (int t = 0; t < 4; ++t) {
        const long row = m0 + wm * 64 + t * 16 + mq;
#pragma unroll
        for (int u = 0; u < 10; ++u) {
            const int colb = wn * 160 + u * 16 + kq * 4;
            float4v bv = (float4v)0.f;
            if (BIAS) bv = *(const float4v*)&biasp[colb];
            short4v s;
#pragma unroll
            for (int r4 = 0; r4 < 4; ++r4)
                s[r4] = f2bs(acc[t][u][r4] + bv[r4]);
            *(short4v*)&out[row * 320 + colb] = s;
        }
    }
}

// ---------------- classifier ----------------
__global__ __launch_bounds__(64) void cls_kernel(
    const short* __restrict__ roots, const float* __restrict__ W_cls,
    const float* __restrict__ b_cls, float* __restrict__ out)
{
    const int b    = blockIdx.x;
    const int lane = threadIdx.x;
    const short* row = roots + (long)b * 640;

    float a0 = 0.f, a1 = 0.f, a2 = 0.f;
#pragma unroll
    for (int i = 0; i < 10; ++i) {
        const int k = lane + 64 * i;
        if (k < 600) {
            const int col = (k < 300) ? k : k + 20;
            const float f = 1.f / (1.f + __expf(-bs2f(row[col])));
            a0 += f * W_cls[k];
            a1 += f * W_cls[600 + k];
            a2 += f * W_cls[1200 + k];
        }
    }
#pragma unroll
    for (int off = 32; off > 0; off >>= 1) {
        a0 += __shfl_down(a0, off);
        a1 += __shfl_down(a1, off);
        a2 += __shfl_down(a2, off);
    }
    if (lane == 0) {
        const float l0 = a0 + b_cls[0];
        const float l1 = a1 + b_cls[1];
        const float l2 = a2 + b_cls[2];
        const float m  = fmaxf(l0, fmaxf(l1, l2));
        const float s  = __expf(l0 - m) + __expf(l1 - m) + __expf(l2 - m);
        const float ls = m + __logf(s);
        out[b * 3 + 0] = l0 - ls;
        out[b * 3 + 1] = l1 - ls;
        out[b * 3 + 2] = l2 - ls;
    }
}

extern "C" void kernel_launch(void* const* d_in, const int* in_sizes, int n_in,
                              void* d_out, int out_size, void* d_ws, size_t ws_size,
                              hipStream_t stream)
{
    const int*   wid    = (const int*)d_in[0];     // (512,2,256) int32
    const float* emb    = (const float*)d_in[1];   // (50000,300) f32
    const float* W_leaf = (const float*)d_in[2];   // (300,300)
    const float* W_h    = (const float*)d_in[3];   // (300,600)
    const float* b_h    = (const float*)d_in[4];   // (300,)
    const float* W_cls  = (const float*)d_in[5];   // (3,600)
    const float* b_cls  = (const float*)d_in[6];   // (3,)
    float* outp = (float*)d_out;                   // (512,3) f32

    (void)in_sizes; (void)n_in; (void)out_size; (void)ws_size;

    // ws layout (peak 252,273,920 B < 256 MiB; 284 MB layout faulted in R4):
    //   hA     @ 0           : 262144*320*2 = 167,772,160
    //   hB     @ 167,772,160 : 131072*320*2 =  83,886,080
    //   emb_bf @ 167,772,160 : 50000*320*2  =  32,000,000  (aliases hB: dead
    //            after leaf GEMM; hB first written by L1, which runs later)
    //   Bleaf  @ 251,658,240 ; Bh @ 251,863,040 ; biasp @ 252,272,640
    char* ws = (char*)d_ws;
    short* hA     = (short*)(ws);
    short* hB     = (short*)(ws + 167772160);
    short* emb_bf = (short*)(ws + 167772160);
    short* Bleaf  = (short*)(ws + 251658240);
    short* Bh     = (short*)(ws + 251863040);
    float* biasp  = (float*)(ws + 252272640);

    conv_emb  <<<(50000 * 80 + 255) / 256, 256, 0, stream>>>(emb, emb_bf);
    conv_wleaf<<<(320 * 320) / 256, 256, 0, stream>>>(W_leaf, Bleaf);
    conv_wh   <<<(320 * 640) / 256, 256, 0, stream>>>(W_h, Bh);
    conv_bias <<<1, 320, 0, stream>>>(b_h, biasp);

    // Leaf: M = 262144, K' = 320 (gather rows of emb_bf)
    mfma_gemm<320, true, false><<<262144 / 128, 256, 0, stream>>>(
        nullptr, wid, emb_bf, Bleaf, biasp, hA);

    // Tree: node m reads prev rows 2m,2m+1 = contiguous 640 bf16 (pads align
    // with Bh's zero k-columns). K' = 640.
    short* cur = hA;
    short* nxt = hB;
    int nodes = 131072;
    for (int l = 0; l < 8; ++l) {
        mfma_gemm<640, false, true><<<nodes / 128, 256, 0, stream>>>(
            cur, nullptr, nullptr, Bh, biasp, nxt);
        short* t = cur; cur = nxt; nxt = t;
        nodes >>= 1;
    }
    // roots: cur == hA, 1024 rows x 320 -> 512 x 640 view

    cls_kernel<<<512, 64, 0, stream>>>(cur, W_cls, b_cls, outp);
}